// Round 18
// baseline (521.083 us; speedup 1.0000x reference)
//
#include <hip/hip_runtime.h>
#include <hip/hip_bf16.h>
#include <math.h>

// ---------------------------------------------------------------------------
// Round 16 (base = round 11, PASSED 393us):
//   k1:  chunk-32 staging (69.6KB LDS -> 2 blocks/CU = 2 waves/SIMD, was 1).
//        Same 64-row/4-wave/K-split structure; in-place reduce (no q_s);
//        per-output fmaf chain ascending k => q BITWISE identical.
//        Plain __launch_bounds__(256) (r12's ",2" hint caused spill).
//   k2:  round-10/11 verbatim (185us; r14/r15 k2 variants REVERTED:
//        k2 is concurrency-bound -> r10's 16-chain MLP layout is best).
//   k1b: round-8 spill-free stats. k0*: validated verbatim.
//   LDS-transpose k2 epilogue BANNED (r3/4/6/9).
// ws = 6,489,120 B (proven).
// ---------------------------------------------------------------------------

#define B_ROWS 16384
#define D_DIM  4096
#define LN_EPS 1e-5f

typedef unsigned short ushortT;
typedef short bf16x8 __attribute__((ext_vector_type(8)));
typedef float f32x4 __attribute__((ext_vector_type(4)));

// ---- ws byte offsets ----
#define G_OFF      0u           // 128*128 f32   = 65536
#define GPART_OFF  65536u       // 16*16384 f32  = 1048576 (dead after k0b)
#define WBAR_OFF   1114112u     // 128 f32
#define HB_OFF     1114624u     // 128 f32
#define SCAL_OFF   1115136u     // 8 f32
#define MUINV_OFF  1115168u     // 16384 float2  = 131072
#define FEATS_OFF  1246240u     // 16384*128 bf16 = 4194304
#define W2T_OFF    5440544u     // 4096*128 bf16  = 1048576
// total 6,489,120 B

__device__ __forceinline__ ushortT f2b(float v) {
  __hip_bfloat16 h = __float2bfloat16(v);
  return *(ushortT*)&h;
}
__device__ __forceinline__ float b2f(ushortT u) {
  __hip_bfloat16 h;
  *(ushortT*)&h = u;
  return __bfloat162float(h);
}
__device__ __forceinline__ float rndbf(float v) { return b2f(f2b(v)); }

#define FMA16(ACC, AV, BV)                                   \
  ACC[0][0] = fmaf(AV.x, BV.x, ACC[0][0]);                   \
  ACC[0][1] = fmaf(AV.x, BV.y, ACC[0][1]);                   \
  ACC[0][2] = fmaf(AV.x, BV.z, ACC[0][2]);                   \
  ACC[0][3] = fmaf(AV.x, BV.w, ACC[0][3]);                   \
  ACC[1][0] = fmaf(AV.y, BV.x, ACC[1][0]);                   \
  ACC[1][1] = fmaf(AV.y, BV.y, ACC[1][1]);                   \
  ACC[1][2] = fmaf(AV.y, BV.z, ACC[1][2]);                   \
  ACC[1][3] = fmaf(AV.y, BV.w, ACC[1][3]);                   \
  ACC[2][0] = fmaf(AV.z, BV.x, ACC[2][0]);                   \
  ACC[2][1] = fmaf(AV.z, BV.y, ACC[2][1]);                   \
  ACC[2][2] = fmaf(AV.z, BV.z, ACC[2][2]);                   \
  ACC[2][3] = fmaf(AV.z, BV.w, ACC[2][3]);                   \
  ACC[3][0] = fmaf(AV.w, BV.x, ACC[3][0]);                   \
  ACC[3][1] = fmaf(AV.w, BV.y, ACC[3][1]);                   \
  ACC[3][2] = fmaf(AV.w, BV.z, ACC[3][2]);                   \
  ACC[3][3] = fmaf(AV.w, BV.w, ACC[3][3]);

// ---------------- K0a: Gpart from bf16-rounded W2 (validated verbatim)
__global__ __launch_bounds__(256) void k0a(const float* __restrict__ W2,
                                           float* __restrict__ gpart) {
  __shared__ float wbt[32][132];
  const int tid = threadIdx.x;
  const int ac = blockIdx.x & 3;
  const int kp = blockIdx.x >> 2;
  const int kbase = kp * 256;
  const int ag = tid >> 5, a0 = ag * 4;
  const int bg = tid & 31, b0 = bg * 4;
  const int sb = tid >> 1;
  const int sk = (tid & 1) * 16;
  float acc[4][4] = {};
  for (int sub = 0; sub < 8; ++sub) {
    const int k0 = kbase + sub * 32;
    const float* wp = W2 + (size_t)sb * D_DIM + k0 + sk;
#pragma unroll
    for (int j4 = 0; j4 < 4; ++j4) {
      float4 v = *(const float4*)(wp + j4 * 4);
      wbt[sk + j4 * 4 + 0][sb] = rndbf(v.x);
      wbt[sk + j4 * 4 + 1][sb] = rndbf(v.y);
      wbt[sk + j4 * 4 + 2][sb] = rndbf(v.z);
      wbt[sk + j4 * 4 + 3][sb] = rndbf(v.w);
    }
    __syncthreads();
#pragma unroll 8
    for (int k = 0; k < 32; ++k) {
      float4 av = *(const float4*)&wbt[k][ac * 32 + a0];
      float4 bv = *(const float4*)&wbt[k][b0];
      FMA16(acc, av, bv)
    }
    __syncthreads();
  }
  float* gp = gpart + (size_t)kp * 16384 + (size_t)(ac * 32 + a0) * 128 + b0;
#pragma unroll
  for (int i = 0; i < 4; ++i) {
    float4 v;
    v.x = acc[i][0]; v.y = acc[i][1]; v.z = acc[i][2]; v.w = acc[i][3];
    *(float4*)(gp + (size_t)i * 128) = v;
  }
}

// ---------------- K0b: reduce partials -> G (validated verbatim)
__global__ __launch_bounds__(256) void k0b(const float* __restrict__ gpart,
                                           float* __restrict__ G) {
  const int e = blockIdx.x * 256 + threadIdx.x;
  float s = 0.f;
#pragma unroll
  for (int p = 0; p < 16; ++p) s += gpart[(size_t)p * 16384 + e];
  G[e] = s;
}

// ---------------- K0c: wbar, hb, scal (validated verbatim)
__global__ __launch_bounds__(256) void k0c(const float* __restrict__ W2,
                                           const float* __restrict__ b2,
                                           float* __restrict__ wbar,
                                           float* __restrict__ hb,
                                           float* __restrict__ scal) {
  __shared__ float r1[256], r2[256];
  const int a = blockIdx.x, t = threadIdx.x;
  float s1 = 0.f, s2 = 0.f;
  if (a < 128) {
    const float* wp = W2 + (size_t)a * D_DIM;
    for (int j = t; j < D_DIM; j += 256) {
      float w = rndbf(wp[j]);
      s1 += w; s2 = fmaf(w, b2[j], s2);
    }
  } else {
    for (int j = t; j < D_DIM; j += 256) { float b = b2[j]; s1 += b; s2 = fmaf(b, b, s2); }
  }
  r1[t] = s1; r2[t] = s2;
  __syncthreads();
  for (int s = 128; s > 0; s >>= 1) {
    if (t < s) { r1[t] += r1[t + s]; r2[t] += r2[t + s]; }
    __syncthreads();
  }
  if (t == 0) {
    if (a < 128) { wbar[a] = r1[0]; hb[a] = r2[0]; }
    else         { scal[0] = r1[0]; scal[1] = r2[0]; }
  }
}

// ---------------- K0e: W2t = transpose(bf16(W2)) (validated verbatim)
__global__ __launch_bounds__(256) void k0e(const float* __restrict__ W2,
                                           ushortT* __restrict__ W2t) {
  __shared__ ushortT tile[32][136];
  const int t = threadIdx.x;
  const int j0 = blockIdx.x * 32;
#pragma unroll
  for (int p = 0; p < 4; ++p) {
    const int a = p * 32 + (t >> 3);
    const int jc = (t & 7) * 4;
    float4 v = *(const float4*)&W2[(size_t)a * D_DIM + j0 + jc];
    tile[jc + 0][a] = f2b(v.x);
    tile[jc + 1][a] = f2b(v.y);
    tile[jc + 2][a] = f2b(v.z);
    tile[jc + 3][a] = f2b(v.w);
  }
  __syncthreads();
  const int j = t >> 3;
  const int a0 = (t & 7) * 16;
  uint4 u0 = *(const uint4*)&tile[j][a0];
  uint4 u1 = *(const uint4*)&tile[j][a0 + 8];
  *(uint4*)&W2t[(size_t)(j0 + j) * 128 + a0] = u0;
  *(uint4*)&W2t[(size_t)(j0 + j) * 128 + a0 + 8] = u1;
}

// ---------------- K1 (single delta): fused GEMM1 + reduce + tanh + circuit,
// chunk-32 staging. 256 blocks x 64 rows; 4 waves, wave w owns k-slice
// w*1024..+1023 in 32 chunks of 32. Per-thread acc[8][8]; lane l stages
// x row l (8 float4) + W1 row l>>1, col half (l&1)*32 (8 float4).
// LDS 69632 B: per-wave xs[32][68]+wsb[32][68]; reduce reuses region,
// in-place tanh into red0. Chain ascending k per output == r11 BITWISE.
__global__ __launch_bounds__(256) void k1(const float* __restrict__ x,
                                          const float* __restrict__ W1,
                                          const float* __restrict__ b1,
                                          ushortT* __restrict__ featsb) {
  extern __shared__ float lds[];
  const int tid = threadIdx.x;
  const int w = tid >> 6, l = tid & 63;
  const size_t row0 = (size_t)blockIdx.x * 64;
  float* xs  = lds + w * 4352;   // [32 k][68 rows]
  float* wsb = xs + 2176;        // [32 k][68 cols]
  const int rg = l >> 3, cg = l & 7;
  const int kw = w * 1024;
  const int wk = l >> 1;         // W1 staging k-row 0..31
  const int wc = (l & 1) * 32;   // W1 staging col offset 0/32
  float acc[8][8] = {};
  float4 xr[8], wr[8];
  // prologue: chunk 0
  {
    const float* xp = x + (row0 + l) * D_DIM + kw;
#pragma unroll
    for (int i = 0; i < 8; ++i) xr[i] = *(const float4*)(xp + i * 4);
    const float* wp = W1 + (size_t)(kw + wk) * 128 + wc;
#pragma unroll
    for (int m = 0; m < 8; ++m) wr[m] = *(const float4*)(wp + m * 4);
  }
  for (int t = 0; t < 32; ++t) {
    // stage x (transpose on write): xs[k][row l]
#pragma unroll
    for (int i = 0; i < 8; ++i) {
      xs[(i * 4 + 0) * 68 + l] = xr[i].x;
      xs[(i * 4 + 1) * 68 + l] = xr[i].y;
      xs[(i * 4 + 2) * 68 + l] = xr[i].z;
      xs[(i * 4 + 3) * 68 + l] = xr[i].w;
    }
#pragma unroll
    for (int m = 0; m < 8; ++m)
      *(float4*)&wsb[wk * 68 + wc + m * 4] = wr[m];
    // prefetch next chunk (global; hides HBM/L2 latency under compute)
    if (t < 31) {
      const int kt2 = kw + (t + 1) * 32;
      const float* xp = x + (row0 + l) * D_DIM + kt2;
#pragma unroll
      for (int i = 0; i < 8; ++i) xr[i] = *(const float4*)(xp + i * 4);
      const float* wp = W1 + (size_t)(kt2 + wk) * 128 + wc;
#pragma unroll
      for (int m = 0; m < 8; ++m) wr[m] = *(const float4*)(wp + m * 4);
    }
    asm volatile("s_waitcnt lgkmcnt(0)" ::: "memory");
    // compute 32 k-steps (same-wave LDS; in-order DS ops make WAR safe)
    for (int k = 0; k < 32; ++k) {
      const float4 xv0 = *(const float4*)&xs[k * 68 + rg * 8];
      const float4 xv1 = *(const float4*)&xs[k * 68 + rg * 8 + 4];
      const float4 wv0 = *(const float4*)&wsb[k * 68 + cg * 8];
      const float4 wv1 = *(const float4*)&wsb[k * 68 + cg * 8 + 4];
      const float xv[8] = {xv0.x, xv0.y, xv0.z, xv0.w, xv1.x, xv1.y, xv1.z, xv1.w};
      const float wv[8] = {wv0.x, wv0.y, wv0.z, wv0.w, wv1.x, wv1.y, wv1.z, wv1.w};
#pragma unroll
      for (int i = 0; i < 8; ++i)
#pragma unroll
        for (int j = 0; j < 8; ++j)
          acc[i][j] = fmaf(xv[i], wv[j], acc[i][j]);
    }
  }
  __syncthreads();  // all waves done with staging; reuse as red[4][64][64]
  {
    float* red = lds + w * 4096;
#pragma unroll
    for (int i = 0; i < 8; ++i) {
      float4 v0, v1;
      v0.x = acc[i][0]; v0.y = acc[i][1]; v0.z = acc[i][2]; v0.w = acc[i][3];
      v1.x = acc[i][4]; v1.y = acc[i][5]; v1.z = acc[i][6]; v1.w = acc[i][7];
      *(float4*)&red[(rg * 8 + i) * 64 + cg * 8] = v0;
      *(float4*)&red[(rg * 8 + i) * 64 + cg * 8 + 4] = v1;
    }
  }
  __syncthreads();
  // reduce 4 slices (((p0+p1)+p2)+p3) + b1 + tanh, IN-PLACE into red0.
  // Each lds[r*64+c] is read and rewritten by the same thread: race-free.
  {
    const int r = tid >> 2, c16 = (tid & 3) * 16;
#pragma unroll
    for (int m = 0; m < 4; ++m) {
      const int c = c16 + 4 * m;
      float4 s  = *(const float4*)&lds[0 * 4096 + r * 64 + c];
      float4 v1 = *(const float4*)&lds[1 * 4096 + r * 64 + c];
      float4 v2 = *(const float4*)&lds[2 * 4096 + r * 64 + c];
      float4 v3 = *(const float4*)&lds[3 * 4096 + r * 64 + c];
      s.x = ((s.x + v1.x) + v2.x) + v3.x;
      s.y = ((s.y + v1.y) + v2.y) + v3.y;
      s.z = ((s.z + v1.z) + v2.z) + v3.z;
      s.w = ((s.w + v1.w) + v2.w) + v3.w;
      float4 q;
      q.x = tanhf(s.x + b1[c + 0]);
      q.y = tanhf(s.y + b1[c + 1]);
      q.z = tanhf(s.z + b1[c + 2]);
      q.w = tanhf(s.w + b1[c + 3]);
      *(float4*)&lds[r * 64 + c] = q;
    }
  }
  __syncthreads();
  // quantum circuit (exact f32 chain, validated verbatim) -> featsb bf16
  if (tid < 64) {
    const int r = tid;
    ushortT* frow = featsb + (row0 + r) * 128;
    const float PI_F = 3.14159274101257324f;
    const float IS2  = 0.707106769084930420f;
    bool swp = false;
    for (int j = 0; j < 32; ++j) {
      float th = lds[r * 64 + 2 * j] * PI_F;
      float ph = lds[r * 64 + 2 * j + 1] * PI_F;
      float hf = 0.5f * th;
      float chf = cosf(hf), shf = sinf(hf);
      float cp = cosf(ph), sp = sinf(ph);
      float ar = chf, ai = 0.0f;
      float br = shf * cp, bi = shf * sp;
      if ((j & 1) == 0) {
        float t1r = (ar + br) * IS2, t1i = (ai + bi) * IS2;
        float t2r = (ar - br) * IS2, t2i = (ai - bi) * IS2;
        ar = t1r; ai = t1i; br = t2r; bi = t2i;
      }
      if (swp) { float t = ar; ar = br; br = t; t = ai; ai = bi; bi = t; }
      ushort4 o;
      o.x = f2b(ar); o.y = f2b(ai); o.z = f2b(br); o.w = f2b(bi);
      *(ushort4*)&frow[4 * j] = o;
      swp = sqrtf(fmaf(br, br, bi * bi)) > 0.5f;
    }
  }
}

// ---------------- K1b: analytic LN stats, spill-free (round-8/11 verbatim)
__global__ __launch_bounds__(256) void k1b(const ushortT* __restrict__ featsb,
                                           const float* __restrict__ G,
                                           const float* __restrict__ wbar,
                                           const float* __restrict__ hb,
                                           const float* __restrict__ scal,
                                           float2* __restrict__ muinv) {
  __shared__ float ftr[128 * 68];
  __shared__ float gbuf[32 * 128];
  __shared__ float e2red[64 * 17];
  const int tid = threadIdx.x;
  const size_t row0 = (size_t)blockIdx.x * 64;
  {
    const int r = tid >> 2;
    const int ks = (tid & 3) * 32;
    const ushortT* fp = featsb + (row0 + r) * 128 + ks;
#pragma unroll
    for (int i = 0; i < 4; ++i) {
      ushort4 u0 = *(const ushort4*)(fp + i * 8);
      ushort4 u1 = *(const ushort4*)(fp + i * 8 + 4);
      ftr[(ks + i * 8 + 0) * 68 + r] = b2f(u0.x);
      ftr[(ks + i * 8 + 1) * 68 + r] = b2f(u0.y);
      ftr[(ks + i * 8 + 2) * 68 + r] = b2f(u0.z);
      ftr[(ks + i * 8 + 3) * 68 + r] = b2f(u0.w);
      ftr[(ks + i * 8 + 4) * 68 + r] = b2f(u1.x);
      ftr[(ks + i * 8 + 5) * 68 + r] = b2f(u1.y);
      ftr[(ks + i * 8 + 6) * 68 + r] = b2f(u1.z);
      ftr[(ks + i * 8 + 7) * 68 + r] = b2f(u1.w);
    }
  }
  const int rloc = tid >> 4;
  const int bo = (tid & 15) * 8;
  const int sal = tid >> 3;
  const int sbo = (tid & 7) * 16;
#pragma unroll 1
  for (int rchk = 0; rchk < 4; ++rchk) {
    const int r = rchk * 16 + rloc;
    float vacc[8] = {0.f, 0.f, 0.f, 0.f, 0.f, 0.f, 0.f, 0.f};
#pragma unroll 1
    for (int gchk = 0; gchk < 4; ++gchk) {
      __syncthreads();
      {
        const float* gp = G + (size_t)(gchk * 32 + sal) * 128 + sbo;
#pragma unroll
        for (int j4 = 0; j4 < 4; ++j4)
          *(float4*)(gbuf + sal * 128 + sbo + j4 * 4) = *(const float4*)(gp + j4 * 4);
      }
      __syncthreads();
#pragma unroll 4
      for (int al = 0; al < 32; ++al) {
        const float fa = ftr[(gchk * 32 + al) * 68 + r];
        const float4 g0 = *(const float4*)&gbuf[al * 128 + bo];
        const float4 g1 = *(const float4*)&gbuf[al * 128 + bo + 4];
        vacc[0] = fmaf(fa, g0.x, vacc[0]);
        vacc[1] = fmaf(fa, g0.y, vacc[1]);
        vacc[2] = fmaf(fa, g0.z, vacc[2]);
        vacc[3] = fmaf(fa, g0.w, vacc[3]);
        vacc[4] = fmaf(fa, g1.x, vacc[4]);
        vacc[5] = fmaf(fa, g1.y, vacc[5]);
        vacc[6] = fmaf(fa, g1.z, vacc[6]);
        vacc[7] = fmaf(fa, g1.w, vacc[7]);
      }
    }
    float e2p = 0.f;
#pragma unroll
    for (int j = 0; j < 8; ++j)
      e2p = fmaf(vacc[j], ftr[(bo + j) * 68 + r], e2p);
    e2red[r * 17 + (tid & 15)] = e2p;
  }
  __syncthreads();
  if (tid < 64) {
    const int r = tid;
    float e2 = 0.f;
#pragma unroll
    for (int p = 0; p < 16; ++p) e2 += e2red[r * 17 + p];
    float mup = 0.f, hbp = 0.f;
#pragma unroll 4
    for (int a = 0; a < 128; ++a) {
      const float fa = ftr[a * 68 + r];
      mup = fmaf(fa, wbar[a], mup);
      hbp = fmaf(fa, hb[a], hbp);
    }
    e2 = fmaf(2.0f, hbp, e2) + scal[1];
    const float mu = (mup + scal[0]) * (1.0f / D_DIM);
    const float var = e2 * (1.0f / D_DIM) - mu * mu;
    float2 mi2;
    mi2.x = mu;
    mi2.y = 1.0f / sqrtf(var + LN_EPS);
    muinv[row0 + r] = mi2;
  }
}

// ---------------- K2: operand-swapped bf16 MFMA GEMM2 + register-domain
// float4 LN+residual epilogue (round-10/11 verbatim, validated, 185us)
__global__ __launch_bounds__(256) void k2(const ushortT* __restrict__ featsb,
                                          const ushortT* __restrict__ W2t,
                                          const float* __restrict__ b2,
                                          const float* __restrict__ gam,
                                          const float* __restrict__ bet,
                                          const float* __restrict__ x,
                                          const float2* __restrict__ muinv,
                                          float* __restrict__ out) {
  const int bid = blockIdx.x;
  const int swz = (bid & 7) * 512 + (bid >> 3);
  const int mblk = swz >> 5, nblk = swz & 31;
  const size_t row0 = (size_t)mblk * 128;
  const size_t col0 = (size_t)nblk * 128;
  const int tid = threadIdx.x;
  const int wid = tid >> 6, lane = tid & 63;
  const int wm = wid >> 1, wn = wid & 1;
  const int lr = lane & 15, lg = lane >> 4;
  f32x4 acc[4][4];
#pragma unroll
  for (int i = 0; i < 4; ++i)
#pragma unroll
    for (int j = 0; j < 4; ++j) acc[i][j] = (f32x4){0.f, 0.f, 0.f, 0.f};
  const ushortT* aBase = featsb + (row0 + wm * 64 + lr) * 128 + lg * 8;
  const ushortT* bBase = W2t + (col0 + wn * 64 + lr) * 128 + lg * 8;
#pragma unroll
  for (int ks = 0; ks < 4; ++ks) {
    bf16x8 a[4], b[4];
#pragma unroll
    for (int mi = 0; mi < 4; ++mi)
      a[mi] = *(const bf16x8*)(aBase + (size_t)mi * 16 * 128 + ks * 32);
#pragma unroll
    for (int ni = 0; ni < 4; ++ni)
      b[ni] = *(const bf16x8*)(bBase + (size_t)ni * 16 * 128 + ks * 32);
#pragma unroll
    for (int mi = 0; mi < 4; ++mi)
#pragma unroll
      for (int ni = 0; ni < 4; ++ni)
        acc[mi][ni] = __builtin_amdgcn_mfma_f32_16x16x32_bf16(b[ni], a[mi], acc[mi][ni], 0, 0, 0);
  }
  float4 b2c[4], gc[4], btc[4];
#pragma unroll
  for (int ni = 0; ni < 4; ++ni) {
    const size_t col = col0 + wn * 64 + ni * 16 + lg * 4;
    b2c[ni] = *(const float4*)(b2 + col);
    gc[ni]  = *(const float4*)(gam + col);
    btc[ni] = *(const float4*)(bet + col);
  }
#pragma unroll
  for (int mi = 0; mi < 4; ++mi) {
    const size_t row = row0 + wm * 64 + mi * 16 + lr;
    const float2 mi2 = muinv[row];
    const float mu = mi2.x, inv = mi2.y;
    const float* xrow = x + row * D_DIM;
    float* orow = out + row * D_DIM;
#pragma unroll
    for (int ni = 0; ni < 4; ++ni) {
      const size_t col = col0 + wn * 64 + ni * 16 + lg * 4;
      const float4 xv = *(const float4*)(xrow + col);
      float4 y;
      y.x = fmaf((acc[mi][ni][0] + b2c[ni].x - mu) * inv, gc[ni].x, btc[ni].x) + xv.x;
      y.y = fmaf((acc[mi][ni][1] + b2c[ni].y - mu) * inv, gc[ni].y, btc[ni].y) + xv.y;
      y.z = fmaf((acc[mi][ni][2] + b2c[ni].z - mu) * inv, gc[ni].z, btc[ni].z) + xv.z;
      y.w = fmaf((acc[mi][ni][3] + b2c[ni].w - mu) * inv, gc[ni].w, btc[ni].w) + xv.w;
      *(float4*)(orow + col) = y;
    }
  }
}

extern "C" void kernel_launch(void* const* d_in, const int* in_sizes, int n_in,
                              void* d_out, int out_size, void* d_ws, size_t ws_size,
                              hipStream_t stream) {
  const float* x = (const float*)d_in[0];
  const float* W1 = (const float*)d_in[1];
  const float* b1 = (const float*)d_in[2];
  const float* W2 = (const float*)d_in[3];
  const float* b2 = (const float*)d_in[4];
  const float* gam = (const float*)d_in[5];
  const float* bet = (const float*)d_in[6];
  float* out = (float*)d_out;
  char* ws = (char*)d_ws;
  float* G = (float*)(ws + G_OFF);
  float* gpart = (float*)(ws + GPART_OFF);
  float* wbar = (float*)(ws + WBAR_OFF);
  float* hbv = (float*)(ws + HB_OFF);
  float* scal = (float*)(ws + SCAL_OFF);
  float2* muinv = (float2*)(ws + MUINV_OFF);
  ushortT* featsb = (ushortT*)(ws + FEATS_OFF);
  ushortT* W2t = (ushortT*)(ws + W2T_OFF);

  hipFuncSetAttribute((const void*)k1, hipFuncAttributeMaxDynamicSharedMemorySize, 69632);

  hipLaunchKernelGGL(k0a, dim3(64), dim3(256), 0, stream, W2, gpart);
  hipLaunchKernelGGL(k0b, dim3(64), dim3(256), 0, stream, gpart, G);
  hipLaunchKernelGGL(k0c, dim3(129), dim3(256), 0, stream, W2, b2, wbar, hbv, scal);
  hipLaunchKernelGGL(k0e, dim3(128), dim3(256), 0, stream, W2, W2t);
  hipLaunchKernelGGL(k1, dim3(B_ROWS / 64), dim3(256), 69632, stream,
                     x, W1, b1, featsb);
  hipLaunchKernelGGL(k1b, dim3(B_ROWS / 64), dim3(256), 0, stream,
                     featsb, G, wbar, hbv, scal, muinv);
  hipLaunchKernelGGL(k2, dim3(4096), dim3(256), 0, stream,
                     featsb, W2t, b2, gam, bet, x, muinv, out);
}

// Round 19
// 518.971 us; speedup vs baseline: 1.0041x; 1.0041x over previous
//
#include <hip/hip_runtime.h>
#include <hip/hip_bf16.h>
#include <math.h>

// ---------------------------------------------------------------------------
// Round 19 = round 18 + ONE delta: k1 __launch_bounds__(256) -> (256, 1).
//   r18's k1 (chunk-32, 69.6KB LDS, 2 blocks/CU possible) is numerically
//   validated (passed, 0.03125) but SPILLED: plain (256) let the compiler
//   cap VGPR at 76 (<130 live floats) -> 90MB scratch writes, 318us.
//   (256,1) gives the 512-VGPR budget (as in r11's k1, no spill); occupancy
//   then comes from LDS: 69.6KB -> 2 blocks/CU = 2 waves/SIMD (r11 had 1).
//   k2:  round-10/11 verbatim (validated, 185us).
//   k1b: round-8 spill-free stats. k0*: validated verbatim.
//   LDS-transpose k2 epilogue BANNED (r3/4/6/9).
// ws = 6,489,120 B (proven).
// ---------------------------------------------------------------------------

#define B_ROWS 16384
#define D_DIM  4096
#define LN_EPS 1e-5f

typedef unsigned short ushortT;
typedef short bf16x8 __attribute__((ext_vector_type(8)));
typedef float f32x4 __attribute__((ext_vector_type(4)));

// ---- ws byte offsets ----
#define G_OFF      0u           // 128*128 f32   = 65536
#define GPART_OFF  65536u       // 16*16384 f32  = 1048576 (dead after k0b)
#define WBAR_OFF   1114112u     // 128 f32
#define HB_OFF     1114624u     // 128 f32
#define SCAL_OFF   1115136u     // 8 f32
#define MUINV_OFF  1115168u     // 16384 float2  = 131072
#define FEATS_OFF  1246240u     // 16384*128 bf16 = 4194304
#define W2T_OFF    5440544u     // 4096*128 bf16  = 1048576
// total 6,489,120 B

__device__ __forceinline__ ushortT f2b(float v) {
  __hip_bfloat16 h = __float2bfloat16(v);
  return *(ushortT*)&h;
}
__device__ __forceinline__ float b2f(ushortT u) {
  __hip_bfloat16 h;
  *(ushortT*)&h = u;
  return __bfloat162float(h);
}
__device__ __forceinline__ float rndbf(float v) { return b2f(f2b(v)); }

#define FMA16(ACC, AV, BV)                                   \
  ACC[0][0] = fmaf(AV.x, BV.x, ACC[0][0]);                   \
  ACC[0][1] = fmaf(AV.x, BV.y, ACC[0][1]);                   \
  ACC[0][2] = fmaf(AV.x, BV.z, ACC[0][2]);                   \
  ACC[0][3] = fmaf(AV.x, BV.w, ACC[0][3]);                   \
  ACC[1][0] = fmaf(AV.y, BV.x, ACC[1][0]);                   \
  ACC[1][1] = fmaf(AV.y, BV.y, ACC[1][1]);                   \
  ACC[1][2] = fmaf(AV.y, BV.z, ACC[1][2]);                   \
  ACC[1][3] = fmaf(AV.y, BV.w, ACC[1][3]);                   \
  ACC[2][0] = fmaf(AV.z, BV.x, ACC[2][0]);                   \
  ACC[2][1] = fmaf(AV.z, BV.y, ACC[2][1]);                   \
  ACC[2][2] = fmaf(AV.z, BV.z, ACC[2][2]);                   \
  ACC[2][3] = fmaf(AV.z, BV.w, ACC[2][3]);                   \
  ACC[3][0] = fmaf(AV.w, BV.x, ACC[3][0]);                   \
  ACC[3][1] = fmaf(AV.w, BV.y, ACC[3][1]);                   \
  ACC[3][2] = fmaf(AV.w, BV.z, ACC[3][2]);                   \
  ACC[3][3] = fmaf(AV.w, BV.w, ACC[3][3]);

// ---------------- K0a: Gpart from bf16-rounded W2 (validated verbatim)
__global__ __launch_bounds__(256) void k0a(const float* __restrict__ W2,
                                           float* __restrict__ gpart) {
  __shared__ float wbt[32][132];
  const int tid = threadIdx.x;
  const int ac = blockIdx.x & 3;
  const int kp = blockIdx.x >> 2;
  const int kbase = kp * 256;
  const int ag = tid >> 5, a0 = ag * 4;
  const int bg = tid & 31, b0 = bg * 4;
  const int sb = tid >> 1;
  const int sk = (tid & 1) * 16;
  float acc[4][4] = {};
  for (int sub = 0; sub < 8; ++sub) {
    const int k0 = kbase + sub * 32;
    const float* wp = W2 + (size_t)sb * D_DIM + k0 + sk;
#pragma unroll
    for (int j4 = 0; j4 < 4; ++j4) {
      float4 v = *(const float4*)(wp + j4 * 4);
      wbt[sk + j4 * 4 + 0][sb] = rndbf(v.x);
      wbt[sk + j4 * 4 + 1][sb] = rndbf(v.y);
      wbt[sk + j4 * 4 + 2][sb] = rndbf(v.z);
      wbt[sk + j4 * 4 + 3][sb] = rndbf(v.w);
    }
    __syncthreads();
#pragma unroll 8
    for (int k = 0; k < 32; ++k) {
      float4 av = *(const float4*)&wbt[k][ac * 32 + a0];
      float4 bv = *(const float4*)&wbt[k][b0];
      FMA16(acc, av, bv)
    }
    __syncthreads();
  }
  float* gp = gpart + (size_t)kp * 16384 + (size_t)(ac * 32 + a0) * 128 + b0;
#pragma unroll
  for (int i = 0; i < 4; ++i) {
    float4 v;
    v.x = acc[i][0]; v.y = acc[i][1]; v.z = acc[i][2]; v.w = acc[i][3];
    *(float4*)(gp + (size_t)i * 128) = v;
  }
}

// ---------------- K0b: reduce partials -> G (validated verbatim)
__global__ __launch_bounds__(256) void k0b(const float* __restrict__ gpart,
                                           float* __restrict__ G) {
  const int e = blockIdx.x * 256 + threadIdx.x;
  float s = 0.f;
#pragma unroll
  for (int p = 0; p < 16; ++p) s += gpart[(size_t)p * 16384 + e];
  G[e] = s;
}

// ---------------- K0c: wbar, hb, scal (validated verbatim)
__global__ __launch_bounds__(256) void k0c(const float* __restrict__ W2,
                                           const float* __restrict__ b2,
                                           float* __restrict__ wbar,
                                           float* __restrict__ hb,
                                           float* __restrict__ scal) {
  __shared__ float r1[256], r2[256];
  const int a = blockIdx.x, t = threadIdx.x;
  float s1 = 0.f, s2 = 0.f;
  if (a < 128) {
    const float* wp = W2 + (size_t)a * D_DIM;
    for (int j = t; j < D_DIM; j += 256) {
      float w = rndbf(wp[j]);
      s1 += w; s2 = fmaf(w, b2[j], s2);
    }
  } else {
    for (int j = t; j < D_DIM; j += 256) { float b = b2[j]; s1 += b; s2 = fmaf(b, b, s2); }
  }
  r1[t] = s1; r2[t] = s2;
  __syncthreads();
  for (int s = 128; s > 0; s >>= 1) {
    if (t < s) { r1[t] += r1[t + s]; r2[t] += r2[t + s]; }
    __syncthreads();
  }
  if (t == 0) {
    if (a < 128) { wbar[a] = r1[0]; hb[a] = r2[0]; }
    else         { scal[0] = r1[0]; scal[1] = r2[0]; }
  }
}

// ---------------- K0e: W2t = transpose(bf16(W2)) (validated verbatim)
__global__ __launch_bounds__(256) void k0e(const float* __restrict__ W2,
                                           ushortT* __restrict__ W2t) {
  __shared__ ushortT tile[32][136];
  const int t = threadIdx.x;
  const int j0 = blockIdx.x * 32;
#pragma unroll
  for (int p = 0; p < 4; ++p) {
    const int a = p * 32 + (t >> 3);
    const int jc = (t & 7) * 4;
    float4 v = *(const float4*)&W2[(size_t)a * D_DIM + j0 + jc];
    tile[jc + 0][a] = f2b(v.x);
    tile[jc + 1][a] = f2b(v.y);
    tile[jc + 2][a] = f2b(v.z);
    tile[jc + 3][a] = f2b(v.w);
  }
  __syncthreads();
  const int j = t >> 3;
  const int a0 = (t & 7) * 16;
  uint4 u0 = *(const uint4*)&tile[j][a0];
  uint4 u1 = *(const uint4*)&tile[j][a0 + 8];
  *(uint4*)&W2t[(size_t)(j0 + j) * 128 + a0] = u0;
  *(uint4*)&W2t[(size_t)(j0 + j) * 128 + a0 + 8] = u1;
}

// ---------------- K1 (single delta vs r18: launch bound (256,1), no spill):
// fused GEMM1 + reduce + tanh + circuit, chunk-32 staging (69.6KB LDS ->
// 2 blocks/CU). Chain ascending k per output == r11 BITWISE.
__global__ __launch_bounds__(256, 1) void k1(const float* __restrict__ x,
                                             const float* __restrict__ W1,
                                             const float* __restrict__ b1,
                                             ushortT* __restrict__ featsb) {
  extern __shared__ float lds[];
  const int tid = threadIdx.x;
  const int w = tid >> 6, l = tid & 63;
  const size_t row0 = (size_t)blockIdx.x * 64;
  float* xs  = lds + w * 4352;   // [32 k][68 rows]
  float* wsb = xs + 2176;        // [32 k][68 cols]
  const int rg = l >> 3, cg = l & 7;
  const int kw = w * 1024;
  const int wk = l >> 1;         // W1 staging k-row 0..31
  const int wc = (l & 1) * 32;   // W1 staging col offset 0/32
  float acc[8][8] = {};
  float4 xr[8], wr[8];
  // prologue: chunk 0
  {
    const float* xp = x + (row0 + l) * D_DIM + kw;
#pragma unroll
    for (int i = 0; i < 8; ++i) xr[i] = *(const float4*)(xp + i * 4);
    const float* wp = W1 + (size_t)(kw + wk) * 128 + wc;
#pragma unroll
    for (int m = 0; m < 8; ++m) wr[m] = *(const float4*)(wp + m * 4);
  }
  for (int t = 0; t < 32; ++t) {
    // stage x (transpose on write): xs[k][row l]
#pragma unroll
    for (int i = 0; i < 8; ++i) {
      xs[(i * 4 + 0) * 68 + l] = xr[i].x;
      xs[(i * 4 + 1) * 68 + l] = xr[i].y;
      xs[(i * 4 + 2) * 68 + l] = xr[i].z;
      xs[(i * 4 + 3) * 68 + l] = xr[i].w;
    }
#pragma unroll
    for (int m = 0; m < 8; ++m)
      *(float4*)&wsb[wk * 68 + wc + m * 4] = wr[m];
    // prefetch next chunk (global; hides HBM/L2 latency under compute)
    if (t < 31) {
      const int kt2 = kw + (t + 1) * 32;
      const float* xp = x + (row0 + l) * D_DIM + kt2;
#pragma unroll
      for (int i = 0; i < 8; ++i) xr[i] = *(const float4*)(xp + i * 4);
      const float* wp = W1 + (size_t)(kt2 + wk) * 128 + wc;
#pragma unroll
      for (int m = 0; m < 8; ++m) wr[m] = *(const float4*)(wp + m * 4);
    }
    asm volatile("s_waitcnt lgkmcnt(0)" ::: "memory");
    // compute 32 k-steps (same-wave LDS; in-order DS ops make WAR safe)
    for (int k = 0; k < 32; ++k) {
      const float4 xv0 = *(const float4*)&xs[k * 68 + rg * 8];
      const float4 xv1 = *(const float4*)&xs[k * 68 + rg * 8 + 4];
      const float4 wv0 = *(const float4*)&wsb[k * 68 + cg * 8];
      const float4 wv1 = *(const float4*)&wsb[k * 68 + cg * 8 + 4];
      const float xv[8] = {xv0.x, xv0.y, xv0.z, xv0.w, xv1.x, xv1.y, xv1.z, xv1.w};
      const float wv[8] = {wv0.x, wv0.y, wv0.z, wv0.w, wv1.x, wv1.y, wv1.z, wv1.w};
#pragma unroll
      for (int i = 0; i < 8; ++i)
#pragma unroll
        for (int j = 0; j < 8; ++j)
          acc[i][j] = fmaf(xv[i], wv[j], acc[i][j]);
    }
  }
  __syncthreads();  // all waves done with staging; reuse as red[4][64][64]
  {
    float* red = lds + w * 4096;
#pragma unroll
    for (int i = 0; i < 8; ++i) {
      float4 v0, v1;
      v0.x = acc[i][0]; v0.y = acc[i][1]; v0.z = acc[i][2]; v0.w = acc[i][3];
      v1.x = acc[i][4]; v1.y = acc[i][5]; v1.z = acc[i][6]; v1.w = acc[i][7];
      *(float4*)&red[(rg * 8 + i) * 64 + cg * 8] = v0;
      *(float4*)&red[(rg * 8 + i) * 64 + cg * 8 + 4] = v1;
    }
  }
  __syncthreads();
  // reduce 4 slices (((p0+p1)+p2)+p3) + b1 + tanh, IN-PLACE into red0.
  {
    const int r = tid >> 2, c16 = (tid & 3) * 16;
#pragma unroll
    for (int m = 0; m < 4; ++m) {
      const int c = c16 + 4 * m;
      float4 s  = *(const float4*)&lds[0 * 4096 + r * 64 + c];
      float4 v1 = *(const float4*)&lds[1 * 4096 + r * 64 + c];
      float4 v2 = *(const float4*)&lds[2 * 4096 + r * 64 + c];
      float4 v3 = *(const float4*)&lds[3 * 4096 + r * 64 + c];
      s.x = ((s.x + v1.x) + v2.x) + v3.x;
      s.y = ((s.y + v1.y) + v2.y) + v3.y;
      s.z = ((s.z + v1.z) + v2.z) + v3.z;
      s.w = ((s.w + v1.w) + v2.w) + v3.w;
      float4 q;
      q.x = tanhf(s.x + b1[c + 0]);
      q.y = tanhf(s.y + b1[c + 1]);
      q.z = tanhf(s.z + b1[c + 2]);
      q.w = tanhf(s.w + b1[c + 3]);
      *(float4*)&lds[r * 64 + c] = q;
    }
  }
  __syncthreads();
  // quantum circuit (exact f32 chain, validated verbatim) -> featsb bf16
  if (tid < 64) {
    const int r = tid;
    ushortT* frow = featsb + (row0 + r) * 128;
    const float PI_F = 3.14159274101257324f;
    const float IS2  = 0.707106769084930420f;
    bool swp = false;
    for (int j = 0; j < 32; ++j) {
      float th = lds[r * 64 + 2 * j] * PI_F;
      float ph = lds[r * 64 + 2 * j + 1] * PI_F;
      float hf = 0.5f * th;
      float chf = cosf(hf), shf = sinf(hf);
      float cp = cosf(ph), sp = sinf(ph);
      float ar = chf, ai = 0.0f;
      float br = shf * cp, bi = shf * sp;
      if ((j & 1) == 0) {
        float t1r = (ar + br) * IS2, t1i = (ai + bi) * IS2;
        float t2r = (ar - br) * IS2, t2i = (ai - bi) * IS2;
        ar = t1r; ai = t1i; br = t2r; bi = t2i;
      }
      if (swp) { float t = ar; ar = br; br = t; t = ai; ai = bi; bi = t; }
      ushort4 o;
      o.x = f2b(ar); o.y = f2b(ai); o.z = f2b(br); o.w = f2b(bi);
      *(ushort4*)&frow[4 * j] = o;
      swp = sqrtf(fmaf(br, br, bi * bi)) > 0.5f;
    }
  }
}

// ---------------- K1b: analytic LN stats, spill-free (round-8/11 verbatim)
__global__ __launch_bounds__(256) void k1b(const ushortT* __restrict__ featsb,
                                           const float* __restrict__ G,
                                           const float* __restrict__ wbar,
                                           const float* __restrict__ hb,
                                           const float* __restrict__ scal,
                                           float2* __restrict__ muinv) {
  __shared__ float ftr[128 * 68];
  __shared__ float gbuf[32 * 128];
  __shared__ float e2red[64 * 17];
  const int tid = threadIdx.x;
  const size_t row0 = (size_t)blockIdx.x * 64;
  {
    const int r = tid >> 2;
    const int ks = (tid & 3) * 32;
    const ushortT* fp = featsb + (row0 + r) * 128 + ks;
#pragma unroll
    for (int i = 0; i < 4; ++i) {
      ushort4 u0 = *(const ushort4*)(fp + i * 8);
      ushort4 u1 = *(const ushort4*)(fp + i * 8 + 4);
      ftr[(ks + i * 8 + 0) * 68 + r] = b2f(u0.x);
      ftr[(ks + i * 8 + 1) * 68 + r] = b2f(u0.y);
      ftr[(ks + i * 8 + 2) * 68 + r] = b2f(u0.z);
      ftr[(ks + i * 8 + 3) * 68 + r] = b2f(u0.w);
      ftr[(ks + i * 8 + 4) * 68 + r] = b2f(u1.x);
      ftr[(ks + i * 8 + 5) * 68 + r] = b2f(u1.y);
      ftr[(ks + i * 8 + 6) * 68 + r] = b2f(u1.z);
      ftr[(ks + i * 8 + 7) * 68 + r] = b2f(u1.w);
    }
  }
  const int rloc = tid >> 4;
  const int bo = (tid & 15) * 8;
  const int sal = tid >> 3;
  const int sbo = (tid & 7) * 16;
#pragma unroll 1
  for (int rchk = 0; rchk < 4; ++rchk) {
    const int r = rchk * 16 + rloc;
    float vacc[8] = {0.f, 0.f, 0.f, 0.f, 0.f, 0.f, 0.f, 0.f};
#pragma unroll 1
    for (int gchk = 0; gchk < 4; ++gchk) {
      __syncthreads();
      {
        const float* gp = G + (size_t)(gchk * 32 + sal) * 128 + sbo;
#pragma unroll
        for (int j4 = 0; j4 < 4; ++j4)
          *(float4*)(gbuf + sal * 128 + sbo + j4 * 4) = *(const float4*)(gp + j4 * 4);
      }
      __syncthreads();
#pragma unroll 4
      for (int al = 0; al < 32; ++al) {
        const float fa = ftr[(gchk * 32 + al) * 68 + r];
        const float4 g0 = *(const float4*)&gbuf[al * 128 + bo];
        const float4 g1 = *(const float4*)&gbuf[al * 128 + bo + 4];
        vacc[0] = fmaf(fa, g0.x, vacc[0]);
        vacc[1] = fmaf(fa, g0.y, vacc[1]);
        vacc[2] = fmaf(fa, g0.z, vacc[2]);
        vacc[3] = fmaf(fa, g0.w, vacc[3]);
        vacc[4] = fmaf(fa, g1.x, vacc[4]);
        vacc[5] = fmaf(fa, g1.y, vacc[5]);
        vacc[6] = fmaf(fa, g1.z, vacc[6]);
        vacc[7] = fmaf(fa, g1.w, vacc[7]);
      }
    }
    float e2p = 0.f;
#pragma unroll
    for (int j = 0; j < 8; ++j)
      e2p = fmaf(vacc[j], ftr[(bo + j) * 68 + r], e2p);
    e2red[r * 17 + (tid & 15)] = e2p;
  }
  __syncthreads();
  if (tid < 64) {
    const int r = tid;
    float e2 = 0.f;
#pragma unroll
    for (int p = 0; p < 16; ++p) e2 += e2red[r * 17 + p];
    float mup = 0.f, hbp = 0.f;
#pragma unroll 4
    for (int a = 0; a < 128; ++a) {
      const float fa = ftr[a * 68 + r];
      mup = fmaf(fa, wbar[a], mup);
      hbp = fmaf(fa, hb[a], hbp);
    }
    e2 = fmaf(2.0f, hbp, e2) + scal[1];
    const float mu = (mup + scal[0]) * (1.0f / D_DIM);
    const float var = e2 * (1.0f / D_DIM) - mu * mu;
    float2 mi2;
    mi2.x = mu;
    mi2.y = 1.0f / sqrtf(var + LN_EPS);
    muinv[row0 + r] = mi2;
  }
}

// ---------------- K2: operand-swapped bf16 MFMA GEMM2 + register-domain
// float4 LN+residual epilogue (round-10/11 verbatim, validated, 185us)
__global__ __launch_bounds__(256) void k2(const ushortT* __restrict__ featsb,
                                          const ushortT* __restrict__ W2t,
                                          const float* __restrict__ b2,
                                          const float* __restrict__ gam,
                                          const float* __restrict__ bet,
                                          const float* __restrict__ x,
                                          const float2* __restrict__ muinv,
                                          float* __restrict__ out) {
  const int bid = blockIdx.x;
  const int swz = (bid & 7) * 512 + (bid >> 3);
  const int mblk = swz >> 5, nblk = swz & 31;
  const size_t row0 = (size_t)mblk * 128;
  const size_t col0 = (size_t)nblk * 128;
  const int tid = threadIdx.x;
  const int wid = tid >> 6, lane = tid & 63;
  const int wm = wid >> 1, wn = wid & 1;
  const int lr = lane & 15, lg = lane >> 4;
  f32x4 acc[4][4];
#pragma unroll
  for (int i = 0; i < 4; ++i)
#pragma unroll
    for (int j = 0; j < 4; ++j) acc[i][j] = (f32x4){0.f, 0.f, 0.f, 0.f};
  const ushortT* aBase = featsb + (row0 + wm * 64 + lr) * 128 + lg * 8;
  const ushortT* bBase = W2t + (col0 + wn * 64 + lr) * 128 + lg * 8;
#pragma unroll
  for (int ks = 0; ks < 4; ++ks) {
    bf16x8 a[4], b[4];
#pragma unroll
    for (int mi = 0; mi < 4; ++mi)
      a[mi] = *(const bf16x8*)(aBase + (size_t)mi * 16 * 128 + ks * 32);
#pragma unroll
    for (int ni = 0; ni < 4; ++ni)
      b[ni] = *(const bf16x8*)(bBase + (size_t)ni * 16 * 128 + ks * 32);
#pragma unroll
    for (int mi = 0; mi < 4; ++mi)
#pragma unroll
      for (int ni = 0; ni < 4; ++ni)
        acc[mi][ni] = __builtin_amdgcn_mfma_f32_16x16x32_bf16(b[ni], a[mi], acc[mi][ni], 0, 0, 0);
  }
  float4 b2c[4], gc[4], btc[4];
#pragma unroll
  for (int ni = 0; ni < 4; ++ni) {
    const size_t col = col0 + wn * 64 + ni * 16 + lg * 4;
    b2c[ni] = *(const float4*)(b2 + col);
    gc[ni]  = *(const float4*)(gam + col);
    btc[ni] = *(const float4*)(bet + col);
  }
#pragma unroll
  for (int mi = 0; mi < 4; ++mi) {
    const size_t row = row0 + wm * 64 + mi * 16 + lr;
    const float2 mi2 = muinv[row];
    const float mu = mi2.x, inv = mi2.y;
    const float* xrow = x + row * D_DIM;
    float* orow = out + row * D_DIM;
#pragma unroll
    for (int ni = 0; ni < 4; ++ni) {
      const size_t col = col0 + wn * 64 + ni * 16 + lg * 4;
      const float4 xv = *(const float4*)(xrow + col);
      float4 y;
      y.x = fmaf((acc[mi][ni][0] + b2c[ni].x - mu) * inv, gc[ni].x, btc[ni].x) + xv.x;
      y.y = fmaf((acc[mi][ni][1] + b2c[ni].y - mu) * inv, gc[ni].y, btc[ni].y) + xv.y;
      y.z = fmaf((acc[mi][ni][2] + b2c[ni].z - mu) * inv, gc[ni].z, btc[ni].z) + xv.z;
      y.w = fmaf((acc[mi][ni][3] + b2c[ni].w - mu) * inv, gc[ni].w, btc[ni].w) + xv.w;
      *(float4*)(orow + col) = y;
    }
  }
}

extern "C" void kernel_launch(void* const* d_in, const int* in_sizes, int n_in,
                              void* d_out, int out_size, void* d_ws, size_t ws_size,
                              hipStream_t stream) {
  const float* x = (const float*)d_in[0];
  const float* W1 = (const float*)d_in[1];
  const float* b1 = (const float*)d_in[2];
  const float* W2 = (const float*)d_in[3];
  const float* b2 = (const float*)d_in[4];
  const float* gam = (const float*)d_in[5];
  const float* bet = (const float*)d_in[6];
  float* out = (float*)d_out;
  char* ws = (char*)d_ws;
  float* G = (float*)(ws + G_OFF);
  float* gpart = (float*)(ws + GPART_OFF);
  float* wbar = (float*)(ws + WBAR_OFF);
  float* hbv = (float*)(ws + HB_OFF);
  float* scal = (float*)(ws + SCAL_OFF);
  float2* muinv = (float2*)(ws + MUINV_OFF);
  ushortT* featsb = (ushortT*)(ws + FEATS_OFF);
  ushortT* W2t = (ushortT*)(ws + W2T_OFF);

  hipFuncSetAttribute((const void*)k1, hipFuncAttributeMaxDynamicSharedMemorySize, 69632);

  hipLaunchKernelGGL(k0a, dim3(64), dim3(256), 0, stream, W2, gpart);
  hipLaunchKernelGGL(k0b, dim3(64), dim3(256), 0, stream, gpart, G);
  hipLaunchKernelGGL(k0c, dim3(129), dim3(256), 0, stream, W2, b2, wbar, hbv, scal);
  hipLaunchKernelGGL(k0e, dim3(128), dim3(256), 0, stream, W2, W2t);
  hipLaunchKernelGGL(k1, dim3(B_ROWS / 64), dim3(256), 69632, stream,
                     x, W1, b1, featsb);
  hipLaunchKernelGGL(k1b, dim3(B_ROWS / 64), dim3(256), 0, stream,
                     featsb, G, wbar, hbv, scal, muinv);
  hipLaunchKernelGGL(k2, dim3(4096), dim3(256), 0, stream,
                     featsb, W2t, b2, gam, bet, x, muinv, out);
}

// Round 20
// 390.596 us; speedup vs baseline: 1.3341x; 1.3287x over previous
//
#include <hip/hip_runtime.h>
#include <hip/hip_bf16.h>
#include <math.h>

// ---------------------------------------------------------------------------
// Round 20: REVERT to round 11 verbatim — the validated best (393us).
// Session evidence (r12-r19, all regressions):
//   - k1 re-tiles for occupancy (r12,r16,r18,r19): hipcc caps VGPR (76) with
//     extern-shared kernels regardless of __launch_bounds__ -> scratch spill.
//   - k2 variants (r14 8-wave, r15 row-band): k2 is concurrency-bound; the
//     r10 4-wave/64x64/16-chain layout is the empirical optimum (185us).
//   - LDS-transpose epilogue BANNED (corruption in r3/4/6/9; bisected r9).
// Config: k1 = fused f32 GEMM1 (8x8 reg tile, 4 waves x K=1024, exact
// ascending-k fmaf chain -- flip-safe) + tanh + circuit; k1b = spill-free
// analytic LN stats; k2 = operand-swapped bf16 MFMA + register epilogue.
// ws = 6,489,120 B (proven).
// ---------------------------------------------------------------------------

#define B_ROWS 16384
#define D_DIM  4096
#define LN_EPS 1e-5f

typedef unsigned short ushortT;
typedef short bf16x8 __attribute__((ext_vector_type(8)));
typedef float f32x4 __attribute__((ext_vector_type(4)));

// ---- ws byte offsets ----
#define G_OFF      0u           // 128*128 f32   = 65536
#define GPART_OFF  65536u       // 16*16384 f32  = 1048576 (dead after k0b)
#define WBAR_OFF   1114112u     // 128 f32
#define HB_OFF     1114624u     // 128 f32
#define SCAL_OFF   1115136u     // 8 f32
#define MUINV_OFF  1115168u     // 16384 float2  = 131072
#define FEATS_OFF  1246240u     // 16384*128 bf16 = 4194304
#define W2T_OFF    5440544u     // 4096*128 bf16  = 1048576
// total 6,489,120 B

__device__ __forceinline__ ushortT f2b(float v) {
  __hip_bfloat16 h = __float2bfloat16(v);
  return *(ushortT*)&h;
}
__device__ __forceinline__ float b2f(ushortT u) {
  __hip_bfloat16 h;
  *(ushortT*)&h = u;
  return __bfloat162float(h);
}
__device__ __forceinline__ float rndbf(float v) { return b2f(f2b(v)); }

#define FMA16(ACC, AV, BV)                                   \
  ACC[0][0] = fmaf(AV.x, BV.x, ACC[0][0]);                   \
  ACC[0][1] = fmaf(AV.x, BV.y, ACC[0][1]);                   \
  ACC[0][2] = fmaf(AV.x, BV.z, ACC[0][2]);                   \
  ACC[0][3] = fmaf(AV.x, BV.w, ACC[0][3]);                   \
  ACC[1][0] = fmaf(AV.y, BV.x, ACC[1][0]);                   \
  ACC[1][1] = fmaf(AV.y, BV.y, ACC[1][1]);                   \
  ACC[1][2] = fmaf(AV.y, BV.z, ACC[1][2]);                   \
  ACC[1][3] = fmaf(AV.y, BV.w, ACC[1][3]);                   \
  ACC[2][0] = fmaf(AV.z, BV.x, ACC[2][0]);                   \
  ACC[2][1] = fmaf(AV.z, BV.y, ACC[2][1]);                   \
  ACC[2][2] = fmaf(AV.z, BV.z, ACC[2][2]);                   \
  ACC[2][3] = fmaf(AV.z, BV.w, ACC[2][3]);                   \
  ACC[3][0] = fmaf(AV.w, BV.x, ACC[3][0]);                   \
  ACC[3][1] = fmaf(AV.w, BV.y, ACC[3][1]);                   \
  ACC[3][2] = fmaf(AV.w, BV.z, ACC[3][2]);                   \
  ACC[3][3] = fmaf(AV.w, BV.w, ACC[3][3]);

// ---------------- K0a: Gpart from bf16-rounded W2 (validated verbatim)
__global__ __launch_bounds__(256) void k0a(const float* __restrict__ W2,
                                           float* __restrict__ gpart) {
  __shared__ float wbt[32][132];
  const int tid = threadIdx.x;
  const int ac = blockIdx.x & 3;
  const int kp = blockIdx.x >> 2;
  const int kbase = kp * 256;
  const int ag = tid >> 5, a0 = ag * 4;
  const int bg = tid & 31, b0 = bg * 4;
  const int sb = tid >> 1;
  const int sk = (tid & 1) * 16;
  float acc[4][4] = {};
  for (int sub = 0; sub < 8; ++sub) {
    const int k0 = kbase + sub * 32;
    const float* wp = W2 + (size_t)sb * D_DIM + k0 + sk;
#pragma unroll
    for (int j4 = 0; j4 < 4; ++j4) {
      float4 v = *(const float4*)(wp + j4 * 4);
      wbt[sk + j4 * 4 + 0][sb] = rndbf(v.x);
      wbt[sk + j4 * 4 + 1][sb] = rndbf(v.y);
      wbt[sk + j4 * 4 + 2][sb] = rndbf(v.z);
      wbt[sk + j4 * 4 + 3][sb] = rndbf(v.w);
    }
    __syncthreads();
#pragma unroll 8
    for (int k = 0; k < 32; ++k) {
      float4 av = *(const float4*)&wbt[k][ac * 32 + a0];
      float4 bv = *(const float4*)&wbt[k][b0];
      FMA16(acc, av, bv)
    }
    __syncthreads();
  }
  float* gp = gpart + (size_t)kp * 16384 + (size_t)(ac * 32 + a0) * 128 + b0;
#pragma unroll
  for (int i = 0; i < 4; ++i) {
    float4 v;
    v.x = acc[i][0]; v.y = acc[i][1]; v.z = acc[i][2]; v.w = acc[i][3];
    *(float4*)(gp + (size_t)i * 128) = v;
  }
}

// ---------------- K0b: reduce partials -> G (validated verbatim)
__global__ __launch_bounds__(256) void k0b(const float* __restrict__ gpart,
                                           float* __restrict__ G) {
  const int e = blockIdx.x * 256 + threadIdx.x;
  float s = 0.f;
#pragma unroll
  for (int p = 0; p < 16; ++p) s += gpart[(size_t)p * 16384 + e];
  G[e] = s;
}

// ---------------- K0c: wbar, hb, scal (validated verbatim)
__global__ __launch_bounds__(256) void k0c(const float* __restrict__ W2,
                                           const float* __restrict__ b2,
                                           float* __restrict__ wbar,
                                           float* __restrict__ hb,
                                           float* __restrict__ scal) {
  __shared__ float r1[256], r2[256];
  const int a = blockIdx.x, t = threadIdx.x;
  float s1 = 0.f, s2 = 0.f;
  if (a < 128) {
    const float* wp = W2 + (size_t)a * D_DIM;
    for (int j = t; j < D_DIM; j += 256) {
      float w = rndbf(wp[j]);
      s1 += w; s2 = fmaf(w, b2[j], s2);
    }
  } else {
    for (int j = t; j < D_DIM; j += 256) { float b = b2[j]; s1 += b; s2 = fmaf(b, b, s2); }
  }
  r1[t] = s1; r2[t] = s2;
  __syncthreads();
  for (int s = 128; s > 0; s >>= 1) {
    if (t < s) { r1[t] += r1[t + s]; r2[t] += r2[t + s]; }
    __syncthreads();
  }
  if (t == 0) {
    if (a < 128) { wbar[a] = r1[0]; hb[a] = r2[0]; }
    else         { scal[0] = r1[0]; scal[1] = r2[0]; }
  }
}

// ---------------- K0e: W2t = transpose(bf16(W2)) (validated verbatim)
__global__ __launch_bounds__(256) void k0e(const float* __restrict__ W2,
                                           ushortT* __restrict__ W2t) {
  __shared__ ushortT tile[32][136];
  const int t = threadIdx.x;
  const int j0 = blockIdx.x * 32;
#pragma unroll
  for (int p = 0; p < 4; ++p) {
    const int a = p * 32 + (t >> 3);
    const int jc = (t & 7) * 4;
    float4 v = *(const float4*)&W2[(size_t)a * D_DIM + j0 + jc];
    tile[jc + 0][a] = f2b(v.x);
    tile[jc + 1][a] = f2b(v.y);
    tile[jc + 2][a] = f2b(v.z);
    tile[jc + 3][a] = f2b(v.w);
  }
  __syncthreads();
  const int j = t >> 3;
  const int a0 = (t & 7) * 16;
  uint4 u0 = *(const uint4*)&tile[j][a0];
  uint4 u1 = *(const uint4*)&tile[j][a0 + 8];
  *(uint4*)&W2t[(size_t)(j0 + j) * 128 + a0] = u0;
  *(uint4*)&W2t[(size_t)(j0 + j) * 128 + a0 + 8] = u1;
}

// ---------------- K1: FUSED GEMM1 + reduce + tanh + circuit -> featsb
// (round-11 verbatim, validated, ~170us)
__global__ __launch_bounds__(256, 1) void k1(const float* __restrict__ x,
                                             const float* __restrict__ W1,
                                             const float* __restrict__ b1,
                                             ushortT* __restrict__ featsb) {
  extern __shared__ float lds[];
  const int tid = threadIdx.x;
  const int w = tid >> 6, l = tid & 63;
  const size_t row0 = (size_t)blockIdx.x * 64;
  float* xs  = lds + w * 8704;        // [64 k][68] transposed x
  float* wsb = xs + 4352;             // [64 k][68] W1 tile
  const int rg = l >> 3, cg = l & 7;
  const int lrow = l >> 3;
  const int lk4 = (l & 7) * 4;
  const int kw = w * 1024;
  float acc[8][8] = {};
  float4 xr[16];
#pragma unroll
  for (int i = 0; i < 16; ++i) {
    const int row = lrow + (i & 7) * 8;
    const int k4 = lk4 + (i >> 3) * 32;
    xr[i] = *(const float4*)&x[(row0 + row) * D_DIM + kw + k4];
  }
  for (int t = 0; t < 16; ++t) {
    const int kt = kw + t * 64;
#pragma unroll
    for (int i = 0; i < 16; ++i) {
      const int wrow = lrow + (i & 7) * 8;
      const int wc4 = lk4 + (i >> 3) * 32;
      float4 v = *(const float4*)&W1[(size_t)(kt + wrow) * 128 + wc4];
      *(float4*)&wsb[wrow * 68 + wc4] = v;
    }
#pragma unroll
    for (int i = 0; i < 16; ++i) {
      const int row = lrow + (i & 7) * 8;
      const int k4 = lk4 + (i >> 3) * 32;
      xs[(k4 + 0) * 68 + row] = xr[i].x;
      xs[(k4 + 1) * 68 + row] = xr[i].y;
      xs[(k4 + 2) * 68 + row] = xr[i].z;
      xs[(k4 + 3) * 68 + row] = xr[i].w;
    }
    if (t < 15) {
      const int kt2 = kt + 64;
#pragma unroll
      for (int i = 0; i < 16; ++i) {
        const int row = lrow + (i & 7) * 8;
        const int k4 = lk4 + (i >> 3) * 32;
        xr[i] = *(const float4*)&x[(row0 + row) * D_DIM + kt2 + k4];
      }
    }
    asm volatile("s_waitcnt lgkmcnt(0)" ::: "memory");
    for (int k = 0; k < 64; ++k) {
      const float4 xv0 = *(const float4*)&xs[k * 68 + rg * 8];
      const float4 xv1 = *(const float4*)&xs[k * 68 + rg * 8 + 4];
      const float4 wv0 = *(const float4*)&wsb[k * 68 + cg * 8];
      const float4 wv1 = *(const float4*)&wsb[k * 68 + cg * 8 + 4];
      const float xv[8] = {xv0.x, xv0.y, xv0.z, xv0.w, xv1.x, xv1.y, xv1.z, xv1.w};
      const float wv[8] = {wv0.x, wv0.y, wv0.z, wv0.w, wv1.x, wv1.y, wv1.z, wv1.w};
#pragma unroll
      for (int i = 0; i < 8; ++i)
#pragma unroll
        for (int j = 0; j < 8; ++j)
          acc[i][j] = fmaf(xv[i], wv[j], acc[i][j]);
    }
  }
  __syncthreads();
  {
    float* red = lds + w * 4096;
#pragma unroll
    for (int i = 0; i < 8; ++i) {
      float4 v0, v1;
      v0.x = acc[i][0]; v0.y = acc[i][1]; v0.z = acc[i][2]; v0.w = acc[i][3];
      v1.x = acc[i][4]; v1.y = acc[i][5]; v1.z = acc[i][6]; v1.w = acc[i][7];
      *(float4*)&red[(rg * 8 + i) * 64 + cg * 8] = v0;
      *(float4*)&red[(rg * 8 + i) * 64 + cg * 8 + 4] = v1;
    }
  }
  __syncthreads();
  float* q_s = lds + 16384;  // [64][68]
  {
    const int r = tid >> 2, c16 = (tid & 3) * 16;
#pragma unroll
    for (int m = 0; m < 4; ++m) {
      const int c = c16 + 4 * m;
      float4 s = *(const float4*)&lds[0 * 4096 + r * 64 + c];
      float4 v1 = *(const float4*)&lds[1 * 4096 + r * 64 + c];
      float4 v2 = *(const float4*)&lds[2 * 4096 + r * 64 + c];
      float4 v3 = *(const float4*)&lds[3 * 4096 + r * 64 + c];
      s.x = ((s.x + v1.x) + v2.x) + v3.x;
      s.y = ((s.y + v1.y) + v2.y) + v3.y;
      s.z = ((s.z + v1.z) + v2.z) + v3.z;
      s.w = ((s.w + v1.w) + v2.w) + v3.w;
      q_s[r * 68 + c + 0] = tanhf(s.x + b1[c + 0]);
      q_s[r * 68 + c + 1] = tanhf(s.y + b1[c + 1]);
      q_s[r * 68 + c + 2] = tanhf(s.z + b1[c + 2]);
      q_s[r * 68 + c + 3] = tanhf(s.w + b1[c + 3]);
    }
  }
  __syncthreads();
  if (tid < 64) {
    const int r = tid;
    ushortT* frow = featsb + (row0 + r) * 128;
    const float PI_F = 3.14159274101257324f;
    const float IS2  = 0.707106769084930420f;
    bool swp = false;
    for (int j = 0; j < 32; ++j) {
      float th = q_s[r * 68 + 2 * j] * PI_F;
      float ph = q_s[r * 68 + 2 * j + 1] * PI_F;
      float hf = 0.5f * th;
      float chf = cosf(hf), shf = sinf(hf);
      float cp = cosf(ph), sp = sinf(ph);
      float ar = chf, ai = 0.0f;
      float br = shf * cp, bi = shf * sp;
      if ((j & 1) == 0) {
        float t1r = (ar + br) * IS2, t1i = (ai + bi) * IS2;
        float t2r = (ar - br) * IS2, t2i = (ai - bi) * IS2;
        ar = t1r; ai = t1i; br = t2r; bi = t2i;
      }
      if (swp) { float t = ar; ar = br; br = t; t = ai; ai = bi; bi = t; }
      ushort4 o;
      o.x = f2b(ar); o.y = f2b(ai); o.z = f2b(br); o.w = f2b(bi);
      *(ushort4*)&frow[4 * j] = o;
      swp = sqrtf(fmaf(br, br, bi * bi)) > 0.5f;
    }
  }
}

// ---------------- K1b: analytic LN stats, spill-free (round-8/11 verbatim)
__global__ __launch_bounds__(256) void k1b(const ushortT* __restrict__ featsb,
                                           const float* __restrict__ G,
                                           const float* __restrict__ wbar,
                                           const float* __restrict__ hb,
                                           const float* __restrict__ scal,
                                           float2* __restrict__ muinv) {
  __shared__ float ftr[128 * 68];
  __shared__ float gbuf[32 * 128];
  __shared__ float e2red[64 * 17];
  const int tid = threadIdx.x;
  const size_t row0 = (size_t)blockIdx.x * 64;
  {
    const int r = tid >> 2;
    const int ks = (tid & 3) * 32;
    const ushortT* fp = featsb + (row0 + r) * 128 + ks;
#pragma unroll
    for (int i = 0; i < 4; ++i) {
      ushort4 u0 = *(const ushort4*)(fp + i * 8);
      ushort4 u1 = *(const ushort4*)(fp + i * 8 + 4);
      ftr[(ks + i * 8 + 0) * 68 + r] = b2f(u0.x);
      ftr[(ks + i * 8 + 1) * 68 + r] = b2f(u0.y);
      ftr[(ks + i * 8 + 2) * 68 + r] = b2f(u0.z);
      ftr[(ks + i * 8 + 3) * 68 + r] = b2f(u0.w);
      ftr[(ks + i * 8 + 4) * 68 + r] = b2f(u1.x);
      ftr[(ks + i * 8 + 5) * 68 + r] = b2f(u1.y);
      ftr[(ks + i * 8 + 6) * 68 + r] = b2f(u1.z);
      ftr[(ks + i * 8 + 7) * 68 + r] = b2f(u1.w);
    }
  }
  const int rloc = tid >> 4;
  const int bo = (tid & 15) * 8;
  const int sal = tid >> 3;
  const int sbo = (tid & 7) * 16;
#pragma unroll 1
  for (int rchk = 0; rchk < 4; ++rchk) {
    const int r = rchk * 16 + rloc;
    float vacc[8] = {0.f, 0.f, 0.f, 0.f, 0.f, 0.f, 0.f, 0.f};
#pragma unroll 1
    for (int gchk = 0; gchk < 4; ++gchk) {
      __syncthreads();
      {
        const float* gp = G + (size_t)(gchk * 32 + sal) * 128 + sbo;
#pragma unroll
        for (int j4 = 0; j4 < 4; ++j4)
          *(float4*)(gbuf + sal * 128 + sbo + j4 * 4) = *(const float4*)(gp + j4 * 4);
      }
      __syncthreads();
#pragma unroll 4
      for (int al = 0; al < 32; ++al) {
        const float fa = ftr[(gchk * 32 + al) * 68 + r];
        const float4 g0 = *(const float4*)&gbuf[al * 128 + bo];
        const float4 g1 = *(const float4*)&gbuf[al * 128 + bo + 4];
        vacc[0] = fmaf(fa, g0.x, vacc[0]);
        vacc[1] = fmaf(fa, g0.y, vacc[1]);
        vacc[2] = fmaf(fa, g0.z, vacc[2]);
        vacc[3] = fmaf(fa, g0.w, vacc[3]);
        vacc[4] = fmaf(fa, g1.x, vacc[4]);
        vacc[5] = fmaf(fa, g1.y, vacc[5]);
        vacc[6] = fmaf(fa, g1.z, vacc[6]);
        vacc[7] = fmaf(fa, g1.w, vacc[7]);
      }
    }
    float e2p = 0.f;
#pragma unroll
    for (int j = 0; j < 8; ++j)
      e2p = fmaf(vacc[j], ftr[(bo + j) * 68 + r], e2p);
    e2red[r * 17 + (tid & 15)] = e2p;
  }
  __syncthreads();
  if (tid < 64) {
    const int r = tid;
    float e2 = 0.f;
#pragma unroll
    for (int p = 0; p < 16; ++p) e2 += e2red[r * 17 + p];
    float mup = 0.f, hbp = 0.f;
#pragma unroll 4
    for (int a = 0; a < 128; ++a) {
      const float fa = ftr[a * 68 + r];
      mup = fmaf(fa, wbar[a], mup);
      hbp = fmaf(fa, hb[a], hbp);
    }
    e2 = fmaf(2.0f, hbp, e2) + scal[1];
    const float mu = (mup + scal[0]) * (1.0f / D_DIM);
    const float var = e2 * (1.0f / D_DIM) - mu * mu;
    float2 mi2;
    mi2.x = mu;
    mi2.y = 1.0f / sqrtf(var + LN_EPS);
    muinv[row0 + r] = mi2;
  }
}

// ---------------- K2: operand-swapped bf16 MFMA GEMM2 + register-domain
// float4 LN+residual epilogue (round-10/11 verbatim, validated, 185us)
__global__ __launch_bounds__(256) void k2(const ushortT* __restrict__ featsb,
                                          const ushortT* __restrict__ W2t,
                                          const float* __restrict__ b2,
                                          const float* __restrict__ gam,
                                          const float* __restrict__ bet,
                                          const float* __restrict__ x,
                                          const float2* __restrict__ muinv,
                                          float* __restrict__ out) {
  const int bid = blockIdx.x;
  const int swz = (bid & 7) * 512 + (bid >> 3);
  const int mblk = swz >> 5, nblk = swz & 31;
  const size_t row0 = (size_t)mblk * 128;
  const size_t col0 = (size_t)nblk * 128;
  const int tid = threadIdx.x;
  const int wid = tid >> 6, lane = tid & 63;
  const int wm = wid >> 1, wn = wid & 1;
  const int lr = lane & 15, lg = lane >> 4;
  f32x4 acc[4][4];
#pragma unroll
  for (int i = 0; i < 4; ++i)
#pragma unroll
    for (int j = 0; j < 4; ++j) acc[i][j] = (f32x4){0.f, 0.f, 0.f, 0.f};
  const ushortT* aBase = featsb + (row0 + wm * 64 + lr) * 128 + lg * 8;
  const ushortT* bBase = W2t + (col0 + wn * 64 + lr) * 128 + lg * 8;
#pragma unroll
  for (int ks = 0; ks < 4; ++ks) {
    bf16x8 a[4], b[4];
#pragma unroll
    for (int mi = 0; mi < 4; ++mi)
      a[mi] = *(const bf16x8*)(aBase + (size_t)mi * 16 * 128 + ks * 32);
#pragma unroll
    for (int ni = 0; ni < 4; ++ni)
      b[ni] = *(const bf16x8*)(bBase + (size_t)ni * 16 * 128 + ks * 32);
#pragma unroll
    for (int mi = 0; mi < 4; ++mi)
#pragma unroll
      for (int ni = 0; ni < 4; ++ni)
        acc[mi][ni] = __builtin_amdgcn_mfma_f32_16x16x32_bf16(b[ni], a[mi], acc[mi][ni], 0, 0, 0);
  }
  float4 b2c[4], gc[4], btc[4];
#pragma unroll
  for (int ni = 0; ni < 4; ++ni) {
    const size_t col = col0 + wn * 64 + ni * 16 + lg * 4;
    b2c[ni] = *(const float4*)(b2 + col);
    gc[ni]  = *(const float4*)(gam + col);
    btc[ni] = *(const float4*)(bet + col);
  }
#pragma unroll
  for (int mi = 0; mi < 4; ++mi) {
    const size_t row = row0 + wm * 64 + mi * 16 + lr;
    const float2 mi2 = muinv[row];
    const float mu = mi2.x, inv = mi2.y;
    const float* xrow = x + row * D_DIM;
    float* orow = out + row * D_DIM;
#pragma unroll
    for (int ni = 0; ni < 4; ++ni) {
      const size_t col = col0 + wn * 64 + ni * 16 + lg * 4;
      const float4 xv = *(const float4*)(xrow + col);
      float4 y;
      y.x = fmaf((acc[mi][ni][0] + b2c[ni].x - mu) * inv, gc[ni].x, btc[ni].x) + xv.x;
      y.y = fmaf((acc[mi][ni][1] + b2c[ni].y - mu) * inv, gc[ni].y, btc[ni].y) + xv.y;
      y.z = fmaf((acc[mi][ni][2] + b2c[ni].z - mu) * inv, gc[ni].z, btc[ni].z) + xv.z;
      y.w = fmaf((acc[mi][ni][3] + b2c[ni].w - mu) * inv, gc[ni].w, btc[ni].w) + xv.w;
      *(float4*)(orow + col) = y;
    }
  }
}

extern "C" void kernel_launch(void* const* d_in, const int* in_sizes, int n_in,
                              void* d_out, int out_size, void* d_ws, size_t ws_size,
                              hipStream_t stream) {
  const float* x = (const float*)d_in[0];
  const float* W1 = (const float*)d_in[1];
  const float* b1 = (const float*)d_in[2];
  const float* W2 = (const float*)d_in[3];
  const float* b2 = (const float*)d_in[4];
  const float* gam = (const float*)d_in[5];
  const float* bet = (const float*)d_in[6];
  float* out = (float*)d_out;
  char* ws = (char*)d_ws;
  float* G = (float*)(ws + G_OFF);
  float* gpart = (float*)(ws + GPART_OFF);
  float* wbar = (float*)(ws + WBAR_OFF);
  float* hbv = (float*)(ws + HB_OFF);
  float* scal = (float*)(ws + SCAL_OFF);
  float2* muinv = (float2*)(ws + MUINV_OFF);
  ushortT* featsb = (ushortT*)(ws + FEATS_OFF);
  ushortT* W2t = (ushortT*)(ws + W2T_OFF);

  hipFuncSetAttribute((const void*)k1, hipFuncAttributeMaxDynamicSharedMemorySize, 139264);

  hipLaunchKernelGGL(k0a, dim3(64), dim3(256), 0, stream, W2, gpart);
  hipLaunchKernelGGL(k0b, dim3(64), dim3(256), 0, stream, gpart, G);
  hipLaunchKernelGGL(k0c, dim3(129), dim3(256), 0, stream, W2, b2, wbar, hbv, scal);
  hipLaunchKernelGGL(k0e, dim3(128), dim3(256), 0, stream, W2, W2t);
  hipLaunchKernelGGL(k1, dim3(B_ROWS / 64), dim3(256), 139264, stream,
                     x, W1, b1, featsb);
  hipLaunchKernelGGL(k1b, dim3(B_ROWS / 64), dim3(256), 0, stream,
                     featsb, G, wbar, hbv, scal, muinv);
  hipLaunchKernelGGL(k2, dim3(4096), dim3(256), 0, stream,
                     featsb, W2t, b2, gam, bet, x, muinv, out);
}